// Round 2
// baseline (974.648 us; speedup 1.0000x reference)
//
#include <hip/hip_runtime.h>
#include <stdint.h>

// Problem constants: H=256, B=64, S=4096.
// scores[b,s] = sum_h v[h] * tanh( sum_{kk<512} W[h,kk]*X[kk,b,s] + bias[b,h] )
//   X[kk] = static_enc rows for kk<256, dynamic_enc rows for kk>=256
// out = softmax_s(scores)

typedef __attribute__((ext_vector_type(8))) short short8;  // 8 bf16 (4 VGPRs)
typedef __attribute__((ext_vector_type(4))) float f32x4;   // MFMA acc

__device__ __forceinline__ unsigned pk_bf16(float a, float b) {
  // RNE round two fp32 -> packed bf16x2 (inputs are finite Gaussians, no NaN)
  unsigned ua = __builtin_bit_cast(unsigned, a);
  unsigned ub = __builtin_bit_cast(unsigned, b);
  ua = (ua + 0x7fffu + ((ua >> 16) & 1u)) >> 16;
  ub = (ub + 0x7fffu + ((ub >> 16) & 1u)) >> 16;
  return ua | (ub << 16);
}

// LDS-visibility-only barrier: drains ds ops (lgkmcnt) but leaves global
// loads (vmcnt) in flight across the barrier. __syncthreads() would emit
// s_waitcnt vmcnt(0) and kill the HBM prefetch pipeline.
__device__ __forceinline__ void barrier_lds() {
  asm volatile("s_waitcnt lgkmcnt(0)\n\ts_barrier" ::: "memory");
}

// ---- Prep (fused): blocks 0..63 -> Wc repack, blocks 64..127 -> bias ----
// Wc uint4 index t = (kt2*16 + mt)*64 + L ; holds W[h=16*mt+(L&15)]
//                                             [kk=32*kt2+8*(L>>4)+j], j=0..7
__global__ __launch_bounds__(256) void prep_all(const float* __restrict__ W,
                                                const float* __restrict__ dh,
                                                uint4* __restrict__ Wc,
                                                float* __restrict__ bias) {
  __shared__ float dl[256];
  if (blockIdx.x < 64) {
    const int t   = blockIdx.x * 256 + threadIdx.x;  // [0, 16384)
    const int L   = t & 63;
    const int mt  = (t >> 6) & 15;
    const int kt2 = t >> 10;                          // [0,16)
    const int h   = mt * 16 + (L & 15);
    const int q   = L >> 4;
    const float* wp = W + h * 768 + kt2 * 32 + q * 8;
    float4 w0 = *(const float4*)(wp);
    float4 w1 = *(const float4*)(wp + 4);
    uint4 d;
    d.x = pk_bf16(w0.x, w0.y);
    d.y = pk_bf16(w0.z, w0.w);
    d.z = pk_bf16(w1.x, w1.y);
    d.w = pk_bf16(w1.z, w1.w);
    Wc[t] = d;
  } else {
    const int b = blockIdx.x - 64, h = threadIdx.x;
    dl[h] = dh[b * 256 + h];
    __syncthreads();
    const float4* wp = (const float4*)(W + h * 768 + 512);
    float acc = 0.f;
#pragma unroll 8
    for (int k4 = 0; k4 < 64; ++k4) {
      float4 wv = wp[k4];
      acc += wv.x * dl[4 * k4] + wv.y * dl[4 * k4 + 1] +
             wv.z * dl[4 * k4 + 2] + wv.w * dl[4 * k4 + 3];
    }
    bias[b * 256 + h] = acc;
  }
}

// ---- Main: fused GEMM (M=256, N=64/block, K=512) + tanh + v-reduce ------
// Block: 256 thr (4 waves). Wave w owns rows [64w,64w+64) x all 64 cols.
// BK=64 per iteration, 8 iterations. Depth-2 register prefetch: f[it&1]
// holds iteration it's rows, loaded 2 iterations earlier (~2 phases of
// latency cover). Per iteration issue order (vmcnt FIFO discipline):
//   [Wc A-frags (L2)] -> sched_barrier -> [pack] -> [HBM prefetch it+2]
//   -> [LDS write] -> lgkm-only barrier -> [MFMA: af wait = vmcnt(8),
//   leaves the 8 HBM prefetch loads in flight]
// LDS tile (32k-slab x 16s) stride 1040 B (65*16 pad).
__global__ __launch_bounds__(256, 4) void attn_main(
    const float* __restrict__ se, const float* __restrict__ de,
    const float* __restrict__ bias, const float* __restrict__ vvec,
    const uint4* __restrict__ Wc, float* __restrict__ scores) {
  __shared__ __align__(16) char xlds[2][8 * 1040];
  __shared__ float part[4][64];

  const int tid  = threadIdx.x;
  const int lane = tid & 63;
  const int w    = tid >> 6;                 // wave id == row-block wm
  const int bb   = blockIdx.x >> 6;          // batch
  const int s0   = (blockIdx.x & 63) * 64;   // s-tile origin

  // staging decomposition: thread covers 8 k-rows x 2 s
  const int tk  = tid >> 5;                  // k-octet in BK=64: 0..7
  const int tsl = tid & 31;                  // s-pair index
  const int ktb = tk >> 2;                   // 32k slab 0/1
  const int qs  = tk & 3;

  const size_t enc_base = (size_t)(bb * 256) * 4096 + (size_t)s0 + 2 * tsl;

  f32x4 acc[4][4];
#pragma unroll
  for (int i = 0; i < 4; ++i)
#pragma unroll
    for (int j = 0; j < 4; ++j) acc[i][j] = (f32x4){0.f, 0.f, 0.f, 0.f};

  float2 f[2][8];
  {  // prologue: iterations 0 and 1 (both static_enc, k0=0 and 64)
    const float* rp0 = se + enc_base + (size_t)(8 * tk) * 4096;
#pragma unroll
    for (int r = 0; r < 8; ++r)
      f[0][r] = *(const float2*)(rp0 + (size_t)r * 4096);
    const float* rp1 = se + enc_base + (size_t)(64 + 8 * tk) * 4096;
#pragma unroll
    for (int r = 0; r < 8; ++r)
      f[1][r] = *(const float2*)(rp1 + (size_t)r * 4096);
  }

#pragma unroll
  for (int it = 0; it < 8; ++it) {
    const int cur = it & 1;

    // 1) A-fragment loads for this iteration (L2-resident Wc) — issued
    //    FIRST so their vmcnt wait does not drain the younger HBM prefetch.
    uint4 av[8];
    {
      const uint4* wg = Wc + ((size_t)(it * 2) * 16 + w * 4) * 64 + lane;
#pragma unroll
      for (int kt2b = 0; kt2b < 2; ++kt2b)
#pragma unroll
        for (int im = 0; im < 4; ++im)
          av[kt2b * 4 + im] = wg[(kt2b * 16 + im) * 64];
    }
    __builtin_amdgcn_sched_barrier(0);  // pin: av issue before f prefetch

    // 2) pack f[cur] (loaded 2 iterations ago) -> bf16
    uint4 dx, dy;
    dx.x = pk_bf16(f[cur][0].x, f[cur][1].x);
    dx.y = pk_bf16(f[cur][2].x, f[cur][3].x);
    dx.z = pk_bf16(f[cur][4].x, f[cur][5].x);
    dx.w = pk_bf16(f[cur][6].x, f[cur][7].x);
    dy.x = pk_bf16(f[cur][0].y, f[cur][1].y);
    dy.y = pk_bf16(f[cur][2].y, f[cur][3].y);
    dy.z = pk_bf16(f[cur][4].y, f[cur][5].y);
    dy.w = pk_bf16(f[cur][6].y, f[cur][7].y);

    // 3) issue HBM prefetch for iteration it+2 into the freed f[cur]
    if (it < 6) {
      const int itn = it + 2;
      const float* srcn = (itn < 4) ? se : de;
      const int k0n = (itn * 64) & 255;
      const float* rp = srcn + enc_base + (size_t)(k0n + 8 * tk) * 4096;
#pragma unroll
      for (int r = 0; r < 8; ++r)
        f[cur][r] = *(const float2*)(rp + (size_t)r * 4096);
    }

    // 4) LDS write (k-transposed: one b128 per s holds 8 consecutive k)
    char* xw = xlds[cur];
    {
      int sl = 2 * tsl, stt = sl >> 4, n = sl & 15;
      *(uint4*)(xw + (ktb * 4 + stt) * 1040 + (qs * 16 + n) * 16) = dx;
      sl = 2 * tsl + 1; stt = sl >> 4; n = sl & 15;
      *(uint4*)(xw + (ktb * 4 + stt) * 1040 + (qs * 16 + n) * 16) = dy;
    }

    // 5) LDS-only barrier: ds ops drained, HBM prefetch stays in flight
    barrier_lds();

    // 6) MFMA over this iteration's 64 K
    const char* xr = xlds[cur];
#pragma unroll
    for (int kt2b = 0; kt2b < 2; ++kt2b) {
      short8 af[4], bfr[4];
#pragma unroll
      for (int im = 0; im < 4; ++im)
        af[im] = __builtin_bit_cast(short8, av[kt2b * 4 + im]);
#pragma unroll
      for (int in = 0; in < 4; ++in)
        bfr[in] = *(const short8*)(xr + (kt2b * 4 + in) * 1040 + lane * 16);
#pragma unroll
      for (int im = 0; im < 4; ++im)
#pragma unroll
        for (int in = 0; in < 4; ++in)
          acc[im][in] = __builtin_amdgcn_mfma_f32_16x16x32_bf16(
              af[im], bfr[in], acc[im][in], 0, 0, 0);
    }
  }

  // ---- epilogue: u -> tanh -> v-weighted sum over h ----
  // C/D layout: col = lane&15, row = (lane>>4)*4 + reg  [m89/m91 verified]
  const int q = lane >> 4;
  float colsum[4] = {0.f, 0.f, 0.f, 0.f};
#pragma unroll
  for (int im = 0; im < 4; ++im) {
#pragma unroll
    for (int r = 0; r < 4; ++r) {
      const int h = w * 64 + im * 16 + q * 4 + r;
      const float vb  = vvec[h];
      const float bsv = bias[bb * 256 + h];
#pragma unroll
      for (int in = 0; in < 4; ++in) {
        float u  = acc[im][in][r] + bsv;
        float ex = __expf(2.0f * u);                       // v_exp
        float th = 1.0f - 2.0f * __builtin_amdgcn_rcpf(1.0f + ex);
        colsum[in] += vb * th;
      }
    }
  }
#pragma unroll
  for (int in = 0; in < 4; ++in) {
    float cv = colsum[in];
    cv += __shfl_xor(cv, 16, 64);
    cv += __shfl_xor(cv, 32, 64);
    if (lane < 16) part[w][in * 16 + lane] = cv;
  }
  __syncthreads();
  if (tid < 64) {
    float sc = part[0][tid] + part[1][tid] + part[2][tid] + part[3][tid];
    scores[(size_t)bb * 4096 + s0 + tid] = sc;
  }
}

// ---- Softmax over S=4096 per batch row; in-place on d_out ---------------
__global__ __launch_bounds__(256) void softmax_k(float* __restrict__ io) {
  __shared__ float red[8];
  const int b = blockIdx.x, tid = threadIdx.x;
  float* sp = io + (size_t)b * 4096;
  float e[16];
  float m = -1e30f;
#pragma unroll
  for (int i = 0; i < 16; ++i) {
    e[i] = sp[tid + i * 256];
    m = fmaxf(m, e[i]);
  }
#pragma unroll
  for (int off = 1; off < 64; off <<= 1) m = fmaxf(m, __shfl_xor(m, off, 64));
  if ((tid & 63) == 0) red[tid >> 6] = m;
  __syncthreads();
  m = fmaxf(fmaxf(red[0], red[1]), fmaxf(red[2], red[3]));
  float sum = 0.f;
#pragma unroll
  for (int i = 0; i < 16; ++i) {
    e[i] = __expf(e[i] - m);
    sum += e[i];
  }
#pragma unroll
  for (int off = 1; off < 64; off <<= 1) sum += __shfl_xor(sum, off, 64);
  if ((tid & 63) == 0) red[4 + (tid >> 6)] = sum;
  __syncthreads();
  sum = red[4] + red[5] + red[6] + red[7];
  const float rs = 1.0f / sum;
#pragma unroll
  for (int i = 0; i < 16; ++i) sp[tid + i * 256] = e[i] * rs;
}

extern "C" void kernel_launch(void* const* d_in, const int* in_sizes, int n_in,
                              void* d_out, int out_size, void* d_ws,
                              size_t ws_size, hipStream_t stream) {
  const float* se = (const float*)d_in[0];  // (64,256,4096)
  const float* de = (const float*)d_in[1];  // (64,256,4096)
  const float* dh = (const float*)d_in[2];  // (64,256)
  const float* v  = (const float*)d_in[3];  // (1,256)
  const float* W  = (const float*)d_in[4];  // (256,768)
  float* out = (float*)d_out;               // (64,4096) -- also scores scratch

  char* ws = (char*)d_ws;
  float* bias = (float*)ws;                   // 64 KB
  uint4* Wc   = (uint4*)(ws + (1 << 16));     // 256 KB bf16 fragment-ordered

  prep_all<<<128, 256, 0, stream>>>(W, dh, Wc, bias);
  attn_main<<<4096, 256, 0, stream>>>(se, de, bias, v, Wc, out);
  softmax_k<<<64, 256, 0, stream>>>(out);
}

// Round 3
// 533.305 us; speedup vs baseline: 1.8276x; 1.8276x over previous
//
#include <hip/hip_runtime.h>
#include <stdint.h>

// Problem constants: H=256, B=64, S=4096.
// scores[b,s] = sum_h v[h] * tanh( sum_{kk<512} W[h,kk]*X[kk,b,s] + bias[b,h] )
//   X[kk] = static_enc rows for kk<256, dynamic_enc rows for kk>=256
// out = softmax_s(scores)

typedef __attribute__((ext_vector_type(8))) short short8;  // 8 bf16 (4 VGPRs)
typedef __attribute__((ext_vector_type(4))) float f32x4;   // MFMA acc

__device__ __forceinline__ unsigned pk_bf16(float a, float b) {
  // RNE round two fp32 -> packed bf16x2 (inputs are finite Gaussians, no NaN)
  unsigned ua = __builtin_bit_cast(unsigned, a);
  unsigned ub = __builtin_bit_cast(unsigned, b);
  ua = (ua + 0x7fffu + ((ua >> 16) & 1u)) >> 16;
  ub = (ub + 0x7fffu + ((ub >> 16) & 1u)) >> 16;
  return ua | (ub << 16);
}

// LDS-visibility-only barrier: drains ds ops (lgkmcnt) but leaves global
// loads (vmcnt) in flight across the barrier. __syncthreads() would emit
// s_waitcnt vmcnt(0) and kill the HBM prefetch pipeline.
__device__ __forceinline__ void barrier_lds() {
  asm volatile("s_waitcnt lgkmcnt(0)\n\ts_barrier" ::: "memory");
}

// ---- Prep (fused): blocks 0..63 -> Wc repack, blocks 64..127 -> bias ----
// Wc uint4 index t = (kt2*16 + mt)*64 + L ; holds W[h=16*mt+(L&15)]
//                                             [kk=32*kt2+8*(L>>4)+j], j=0..7
__global__ __launch_bounds__(256) void prep_all(const float* __restrict__ W,
                                                const float* __restrict__ dh,
                                                uint4* __restrict__ Wc,
                                                float* __restrict__ bias) {
  __shared__ float dl[256];
  if (blockIdx.x < 64) {
    const int t   = blockIdx.x * 256 + threadIdx.x;  // [0, 16384)
    const int L   = t & 63;
    const int mt  = (t >> 6) & 15;
    const int kt2 = t >> 10;                          // [0,16)
    const int h   = mt * 16 + (L & 15);
    const int q   = L >> 4;
    const float* wp = W + h * 768 + kt2 * 32 + q * 8;
    float4 w0 = *(const float4*)(wp);
    float4 w1 = *(const float4*)(wp + 4);
    uint4 d;
    d.x = pk_bf16(w0.x, w0.y);
    d.y = pk_bf16(w0.z, w0.w);
    d.z = pk_bf16(w1.x, w1.y);
    d.w = pk_bf16(w1.z, w1.w);
    Wc[t] = d;
  } else {
    const int b = blockIdx.x - 64, h = threadIdx.x;
    dl[h] = dh[b * 256 + h];
    __syncthreads();
    const float4* wp = (const float4*)(W + h * 768 + 512);
    float acc = 0.f;
#pragma unroll 8
    for (int k4 = 0; k4 < 64; ++k4) {
      float4 wv = wp[k4];
      acc += wv.x * dl[4 * k4] + wv.y * dl[4 * k4 + 1] +
             wv.z * dl[4 * k4 + 2] + wv.w * dl[4 * k4 + 3];
    }
    bias[b * 256 + h] = acc;
  }
}

// ---- Main: fused GEMM (M=256, N=64/block, K=512) + tanh + v-reduce ------
// Block: 256 thr (4 waves). Wave w owns rows [64w,64w+64) x all 64 cols.
// BK=64 per iteration, 8 iterations. Depth-2 register prefetch: f[it&1]
// holds iteration it's rows, loaded 2 iterations earlier. Per-iteration
// issue order (vmcnt FIFO discipline):
//   [Wc A-frags (L2)] -> sched_barrier -> [pack f[cur]] ->
//   [HBM prefetch it+2 into freed f[cur]] -> [LDS write] ->
//   lgkm-only barrier -> [MFMA: af wait = vmcnt(8), HBM prefetch stays
//   in flight across the whole MFMA phase]
// NOTE: no __launch_bounds__ waves-arg — R2 showed capping VGPRs here
// spills ~1.8 GB/launch to scratch (WRITE_SIZE 1 KB -> 1.2 GB).
__global__ __launch_bounds__(256) void attn_main(
    const float* __restrict__ se, const float* __restrict__ de,
    const float* __restrict__ bias, const float* __restrict__ vvec,
    const uint4* __restrict__ Wc, float* __restrict__ scores) {
  __shared__ __align__(16) char xlds[2][8 * 1040];
  __shared__ float part[4][64];

  const int tid  = threadIdx.x;
  const int lane = tid & 63;
  const int w    = tid >> 6;                 // wave id == row-block wm
  const int bb   = blockIdx.x >> 6;          // batch
  const int s0   = (blockIdx.x & 63) * 64;   // s-tile origin

  // staging decomposition: thread covers 8 k-rows x 2 s
  const int tk  = tid >> 5;                  // k-octet in BK=64: 0..7
  const int tsl = tid & 31;                  // s-pair index
  const int ktb = tk >> 2;                   // 32k slab 0/1
  const int qs  = tk & 3;

  const size_t enc_base = (size_t)(bb * 256) * 4096 + (size_t)s0 + 2 * tsl;

  f32x4 acc[4][4];
#pragma unroll
  for (int i = 0; i < 4; ++i)
#pragma unroll
    for (int j = 0; j < 4; ++j) acc[i][j] = (f32x4){0.f, 0.f, 0.f, 0.f};

  float2 f[2][8];
  {  // prologue: iterations 0 and 1 (both static_enc, k0=0 and 64)
    const float* rp0 = se + enc_base + (size_t)(8 * tk) * 4096;
#pragma unroll
    for (int r = 0; r < 8; ++r)
      f[0][r] = *(const float2*)(rp0 + (size_t)r * 4096);
    const float* rp1 = se + enc_base + (size_t)(64 + 8 * tk) * 4096;
#pragma unroll
    for (int r = 0; r < 8; ++r)
      f[1][r] = *(const float2*)(rp1 + (size_t)r * 4096);
  }

#pragma unroll
  for (int it = 0; it < 8; ++it) {
    const int cur = it & 1;

    // 1) A-fragment loads for this iteration (L2-resident Wc) — issued
    //    FIRST so their vmcnt wait does not drain the younger HBM prefetch.
    uint4 av[8];
    {
      const uint4* wg = Wc + ((size_t)(it * 2) * 16 + w * 4) * 64 + lane;
#pragma unroll
      for (int kt2b = 0; kt2b < 2; ++kt2b)
#pragma unroll
        for (int im = 0; im < 4; ++im)
          av[kt2b * 4 + im] = wg[(kt2b * 16 + im) * 64];
    }
    __builtin_amdgcn_sched_barrier(0);  // pin: av issue before f prefetch

    // 2) pack f[cur] (loaded 2 iterations ago) -> bf16
    uint4 dx, dy;
    dx.x = pk_bf16(f[cur][0].x, f[cur][1].x);
    dx.y = pk_bf16(f[cur][2].x, f[cur][3].x);
    dx.z = pk_bf16(f[cur][4].x, f[cur][5].x);
    dx.w = pk_bf16(f[cur][6].x, f[cur][7].x);
    dy.x = pk_bf16(f[cur][0].y, f[cur][1].y);
    dy.y = pk_bf16(f[cur][2].y, f[cur][3].y);
    dy.z = pk_bf16(f[cur][4].y, f[cur][5].y);
    dy.w = pk_bf16(f[cur][6].y, f[cur][7].y);

    // 3) issue HBM prefetch for iteration it+2 into the freed f[cur]
    if (it < 6) {
      const int itn = it + 2;
      const float* srcn = (itn < 4) ? se : de;
      const int k0n = (itn * 64) & 255;
      const float* rp = srcn + enc_base + (size_t)(k0n + 8 * tk) * 4096;
#pragma unroll
      for (int r = 0; r < 8; ++r)
        f[cur][r] = *(const float2*)(rp + (size_t)r * 4096);
    }

    // 4) LDS write (k-transposed: one b128 per s holds 8 consecutive k)
    char* xw = xlds[cur];
    {
      int sl = 2 * tsl, stt = sl >> 4, n = sl & 15;
      *(uint4*)(xw + (ktb * 4 + stt) * 1040 + (qs * 16 + n) * 16) = dx;
      sl = 2 * tsl + 1; stt = sl >> 4; n = sl & 15;
      *(uint4*)(xw + (ktb * 4 + stt) * 1040 + (qs * 16 + n) * 16) = dy;
    }

    // 5) LDS-only barrier: ds ops drained, HBM prefetch stays in flight
    barrier_lds();

    // 6) MFMA over this iteration's 64 K
    const char* xr = xlds[cur];
#pragma unroll
    for (int kt2b = 0; kt2b < 2; ++kt2b) {
      short8 af[4], bfr[4];
#pragma unroll
      for (int im = 0; im < 4; ++im)
        af[im] = __builtin_bit_cast(short8, av[kt2b * 4 + im]);
#pragma unroll
      for (int in = 0; in < 4; ++in)
        bfr[in] = *(const short8*)(xr + (kt2b * 4 + in) * 1040 + lane * 16);
#pragma unroll
      for (int im = 0; im < 4; ++im)
#pragma unroll
        for (int in = 0; in < 4; ++in)
          acc[im][in] = __builtin_amdgcn_mfma_f32_16x16x32_bf16(
              af[im], bfr[in], acc[im][in], 0, 0, 0);
    }
  }

  // ---- epilogue: u -> tanh -> v-weighted sum over h ----
  // C/D layout: col = lane&15, row = (lane>>4)*4 + reg  [m89/m91 verified]
  const int q = lane >> 4;
  float colsum[4] = {0.f, 0.f, 0.f, 0.f};
#pragma unroll
  for (int im = 0; im < 4; ++im) {
#pragma unroll
    for (int r = 0; r < 4; ++r) {
      const int h = w * 64 + im * 16 + q * 4 + r;
      const float vb  = vvec[h];
      const float bsv = bias[bb * 256 + h];
#pragma unroll
      for (int in = 0; in < 4; ++in) {
        float u  = acc[im][in][r] + bsv;
        float ex = __expf(2.0f * u);                       // v_exp
        float th = 1.0f - 2.0f * __builtin_amdgcn_rcpf(1.0f + ex);
        colsum[in] += vb * th;
      }
    }
  }
#pragma unroll
  for (int in = 0; in < 4; ++in) {
    float cv = colsum[in];
    cv += __shfl_xor(cv, 16, 64);
    cv += __shfl_xor(cv, 32, 64);
    if (lane < 16) part[w][in * 16 + lane] = cv;
  }
  __syncthreads();
  if (tid < 64) {
    float sc = part[0][tid] + part[1][tid] + part[2][tid] + part[3][tid];
    scores[(size_t)bb * 4096 + s0 + tid] = sc;
  }
}

// ---- Softmax over S=4096 per batch row; in-place on d_out ---------------
__global__ __launch_bounds__(256) void softmax_k(float* __restrict__ io) {
  __shared__ float red[8];
  const int b = blockIdx.x, tid = threadIdx.x;
  float* sp = io + (size_t)b * 4096;
  float e[16];
  float m = -1e30f;
#pragma unroll
  for (int i = 0; i < 16; ++i) {
    e[i] = sp[tid + i * 256];
    m = fmaxf(m, e[i]);
  }
#pragma unroll
  for (int off = 1; off < 64; off <<= 1) m = fmaxf(m, __shfl_xor(m, off, 64));
  if ((tid & 63) == 0) red[tid >> 6] = m;
  __syncthreads();
  m = fmaxf(fmaxf(red[0], red[1]), fmaxf(red[2], red[3]));
  float sum = 0.f;
#pragma unroll
  for (int i = 0; i < 16; ++i) {
    e[i] = __expf(e[i] - m);
    sum += e[i];
  }
#pragma unroll
  for (int off = 1; off < 64; off <<= 1) sum += __shfl_xor(sum, off, 64);
  if ((tid & 63) == 0) red[4 + (tid >> 6)] = sum;
  __syncthreads();
  sum = red[4] + red[5] + red[6] + red[7];
  const float rs = 1.0f / sum;
#pragma unroll
  for (int i = 0; i < 16; ++i) sp[tid + i * 256] = e[i] * rs;
}

extern "C" void kernel_launch(void* const* d_in, const int* in_sizes, int n_in,
                              void* d_out, int out_size, void* d_ws,
                              size_t ws_size, hipStream_t stream) {
  const float* se = (const float*)d_in[0];  // (64,256,4096)
  const float* de = (const float*)d_in[1];  // (64,256,4096)
  const float* dh = (const float*)d_in[2];  // (64,256)
  const float* v  = (const float*)d_in[3];  // (1,256)
  const float* W  = (const float*)d_in[4];  // (256,768)
  float* out = (float*)d_out;               // (64,4096) -- also scores scratch

  char* ws = (char*)d_ws;
  float* bias = (float*)ws;                   // 64 KB
  uint4* Wc   = (uint4*)(ws + (1 << 16));     // 256 KB bf16 fragment-ordered

  prep_all<<<128, 256, 0, stream>>>(W, dh, Wc, bias);
  attn_main<<<4096, 256, 0, stream>>>(se, de, bias, v, Wc, out);
  softmax_k<<<64, 256, 0, stream>>>(out);
}